// Round 4
// baseline (50.038 us; speedup 1.0000x reference)
//
#include <hip/hip_runtime.h>
#include <hip/hip_bf16.h>

// Kernel 1: one WAVE per row (512 blocks x 1024 threads = 8192 waves = one
// wave per row, all resident simultaneously). trapz integral of
// (y_pred - y_true) over [0, idx[b]]:
//   integral = sum_{j=0..id} d_j - 0.5*(d_0 + d_id)
// Bulk loop is branch-free float4; lane 0 applies the end correction,
// squares, and writes err_sq[b]. No LDS, no __syncthreads.
__global__ __launch_bounds__(1024, 2) void row_integral_kernel(
    const float* __restrict__ yp, const float* __restrict__ yt,
    const int* __restrict__ fidx, float* __restrict__ err_sq, int N) {
    const int wave = threadIdx.x >> 6;              // 0..15
    const int lane = threadIdx.x & 63;
    const int b = (blockIdx.x << 4) + wave;         // row index
    const float* __restrict__ p = yp + (size_t)b * N;
    const float* __restrict__ t = yt + (size_t)b * N;
    const int id = fidx[b];

    float sum = 0.0f;
    if (id > 0) {
        const int nchunk = (id >> 2) + 1;           // float4 chunks covering 0..id
        const float4* __restrict__ p4 = (const float4*)p;
        const float4* __restrict__ t4 = (const float4*)t;
        for (int c = lane; c < nchunk; c += 64) {
            const int j0 = c << 2;
            float4 a = p4[c];
            float4 q = t4[c];
            float d0 = a.x - q.x;
            float d1 = a.y - q.y;
            float d2 = a.z - q.z;
            float d3 = a.w - q.w;
            if (j0 + 3 <= id) {
                sum += (d0 + d1) + (d2 + d3);       // interior: branch-free
            } else {
                sum += d0;                           // j0 <= id guaranteed
                if (j0 + 1 <= id) sum += d1;
                if (j0 + 2 <= id) sum += d2;
            }
        }
    }

    // wave64 butterfly reduce (result valid in lane 0)
    for (int o = 32; o > 0; o >>= 1) sum += __shfl_down(sum, o);

    if (lane == 0) {
        float total = sum;
        if (id > 0) {
            total -= 0.5f * ((p[0] - t[0]) + (p[id] - t[id]));
        }
        err_sq[b] = total * total;
    }
}

// Kernel 2: single block, deterministic reduction of B floats -> mean.
__global__ __launch_bounds__(256) void reduce_mean_kernel(
    const float* __restrict__ err_sq, float* __restrict__ out, int B) {
    const float4* __restrict__ e4 = (const float4*)err_sq;
    const int n4 = B >> 2;
    float s = 0.0f;
    for (int i = threadIdx.x; i < n4; i += 256) {
        float4 v = e4[i];
        s += (v.x + v.y) + (v.z + v.w);
    }
    for (int i = (n4 << 2) + threadIdx.x; i < B; i += 256) s += err_sq[i];

    for (int o = 32; o > 0; o >>= 1) s += __shfl_down(s, o);
    __shared__ float part[4];
    const int lane = threadIdx.x & 63;
    const int wid = threadIdx.x >> 6;
    if (lane == 0) part[wid] = s;
    __syncthreads();
    if (threadIdx.x == 0) {
        out[0] = (part[0] + part[1] + part[2] + part[3]) / (float)B;
    }
}

extern "C" void kernel_launch(void* const* d_in, const int* in_sizes, int n_in,
                              void* d_out, int out_size, void* d_ws, size_t ws_size,
                              hipStream_t stream) {
    const float* yp = (const float*)d_in[0];
    const float* yt = (const float*)d_in[1];
    const int* fidx = (const int*)d_in[2];
    float* out = (float*)d_out;
    float* err_sq = (float*)d_ws;

    const int B = in_sizes[2];           // 8192
    const int N = in_sizes[0] / B;       // 4096

    row_integral_kernel<<<B / 16, 1024, 0, stream>>>(yp, yt, fidx, err_sq, N);
    reduce_mean_kernel<<<1, 256, 0, stream>>>(err_sq, out, B);
}

// Round 5
// 36.361 us; speedup vs baseline: 1.3761x; 1.3761x over previous
//
#include <hip/hip_runtime.h>
#include <hip/hip_bf16.h>

#define QCHUNK 256   // float4 chunks per quarter-block (256 chunks = 1024 elems)

// Kernel 1: 4 blocks per row, 256 threads each. Block (b,q) handles float4
// chunks [q*256, min(nchunk, (q+1)*256)) of row b, where
// nchunk = (id>0) ? (id>>2)+1 : 0. Each thread touches at most ONE chunk of
// each array -> perfectly uniform work granularity for HW load balancing.
// Trapz weights (0.5 at j==0 and j==id, 1 inside, 0 beyond) applied
// per element. Writes partial integral sum to part[q*B + b] (0 if empty).
__global__ __launch_bounds__(256) void quarter_integral_kernel(
    const float* __restrict__ yp, const float* __restrict__ yt,
    const int* __restrict__ fidx, float* __restrict__ part, int N, int B) {
    const int blk = blockIdx.x;
    const int b = blk >> 2;
    const int q = blk & 3;
    const int id = fidx[b];
    const int nchunk = (id > 0) ? ((id >> 2) + 1) : 0;

    const float4* __restrict__ p4 = (const float4*)(yp + (size_t)b * N);
    const float4* __restrict__ t4 = (const float4*)(yt + (size_t)b * N);

    float s = 0.0f;
    const int c = (q << 8) + threadIdx.x;   // global chunk index
    if (c < nchunk) {
        const int j0 = c << 2;
        float4 a = p4[c];
        float4 w = t4[c];
        float d0 = a.x - w.x;
        float d1 = a.y - w.y;
        float d2 = a.z - w.z;
        float d3 = a.w - w.w;
        if (j0 > 0 && j0 + 3 < id) {
            s = (d0 + d1) + (d2 + d3);               // interior fast path
        } else {
            // j0 <= id guaranteed (c < nchunk)
            s = ((j0 == 0 || j0 == id) ? 0.5f : 1.0f) * d0;
            if (j0 + 1 <= id) s += ((j0 + 1 == id) ? 0.5f : 1.0f) * d1;
            if (j0 + 2 <= id) s += ((j0 + 2 == id) ? 0.5f : 1.0f) * d2;
            if (j0 + 3 <= id) s += ((j0 + 3 == id) ? 0.5f : 1.0f) * d3;
        }
    }

    // wave64 reduce
    for (int o = 32; o > 0; o >>= 1) s += __shfl_down(s, o);

    __shared__ float lds[4];
    const int lane = threadIdx.x & 63;
    const int wid = threadIdx.x >> 6;
    if (lane == 0) lds[wid] = s;
    __syncthreads();
    if (threadIdx.x == 0) {
        // Always write (ws is poisoned, never re-zeroed between replays)
        part[(size_t)q * B + b] = lds[0] + lds[1] + lds[2] + lds[3];
    }
}

// Kernel 2: single block. Per row: sum the 4 quarter partials, square,
// accumulate; write mean. Deterministic fixed-order reduction.
__global__ __launch_bounds__(1024) void reduce_mean_kernel(
    const float* __restrict__ part, float* __restrict__ out, int B) {
    float s = 0.0f;
    for (int b = threadIdx.x; b < B; b += 1024) {
        float tot = part[b] + part[B + b] + part[2 * B + b] + part[3 * B + b];
        s += tot * tot;
    }
    for (int o = 32; o > 0; o >>= 1) s += __shfl_down(s, o);
    __shared__ float lds[16];
    const int lane = threadIdx.x & 63;
    const int wid = threadIdx.x >> 6;
    if (lane == 0) lds[wid] = s;
    __syncthreads();
    if (threadIdx.x == 0) {
        float total = 0.0f;
        for (int w = 0; w < 16; ++w) total += lds[w];
        out[0] = total / (float)B;
    }
}

extern "C" void kernel_launch(void* const* d_in, const int* in_sizes, int n_in,
                              void* d_out, int out_size, void* d_ws, size_t ws_size,
                              hipStream_t stream) {
    const float* yp = (const float*)d_in[0];
    const float* yt = (const float*)d_in[1];
    const int* fidx = (const int*)d_in[2];
    float* out = (float*)d_out;
    float* part = (float*)d_ws;          // 4*B floats

    const int B = in_sizes[2];           // 8192
    const int N = in_sizes[0] / B;       // 4096

    quarter_integral_kernel<<<B * 4, 256, 0, stream>>>(yp, yt, fidx, part, N, B);
    reduce_mean_kernel<<<1, 1024, 0, stream>>>(part, out, B);
}

// Round 6
// 31.585 us; speedup vs baseline: 1.5842x; 1.1512x over previous
//
#include <hip/hip_runtime.h>
#include <hip/hip_bf16.h>

#define BLOCK 256
#define HCHUNK 512   // float4 chunks per half-row (512 chunks = 2048 elems)

// Kernel 1: 2 blocks per row, 256 threads each. Block (b,h) handles float4
// chunks [h*512, min(nchunk,(h+1)*512)) of row b, where
// nchunk = (id>0) ? (id>>2)+1 : 0.  <=2 iterations per thread.
// Trapz weights (0.5 at j==0 and j==id, 1 inside, 0 beyond) applied per
// element; interior chunks take the branch-free fast path (only the chunk
// containing j==0 or j==id is slow). Writes partial integral to
// part[h*B + b] (always writes: ws is poisoned, never re-zeroed).
__global__ __launch_bounds__(BLOCK) void half_integral_kernel(
    const float* __restrict__ yp, const float* __restrict__ yt,
    const int* __restrict__ fidx, float* __restrict__ part, int N, int B) {
    const int blk = blockIdx.x;
    const int b = blk >> 1;
    const int h = blk & 1;
    const int id = fidx[b];
    const int nchunk = (id > 0) ? ((id >> 2) + 1) : 0;
    const int cend = min(nchunk, (h + 1) * HCHUNK);

    const float4* __restrict__ p4 = (const float4*)(yp + (size_t)b * N);
    const float4* __restrict__ t4 = (const float4*)(yt + (size_t)b * N);

    float s = 0.0f;
    for (int c = (h * HCHUNK) + threadIdx.x; c < cend; c += BLOCK) {
        const int j0 = c << 2;
        float4 a = p4[c];
        float4 w = t4[c];
        float d0 = a.x - w.x;
        float d1 = a.y - w.y;
        float d2 = a.z - w.z;
        float d3 = a.w - w.w;
        if (j0 > 0 && j0 + 3 < id) {
            s += (d0 + d1) + (d2 + d3);              // interior fast path
        } else {
            // j0 <= id guaranteed (c < nchunk)
            s += ((j0 == 0 || j0 == id) ? 0.5f : 1.0f) * d0;
            if (j0 + 1 <= id) s += ((j0 + 1 == id) ? 0.5f : 1.0f) * d1;
            if (j0 + 2 <= id) s += ((j0 + 2 == id) ? 0.5f : 1.0f) * d2;
            if (j0 + 3 <= id) s += ((j0 + 3 == id) ? 0.5f : 1.0f) * d3;
        }
    }

    // wave64 reduce
    for (int o = 32; o > 0; o >>= 1) s += __shfl_down(s, o);

    __shared__ float lds[4];
    const int lane = threadIdx.x & 63;
    const int wid = threadIdx.x >> 6;
    if (lane == 0) lds[wid] = s;
    __syncthreads();
    if (threadIdx.x == 0) {
        part[(size_t)h * B + b] = lds[0] + lds[1] + lds[2] + lds[3];
    }
}

// Kernel 2: single block. Per row: sum the 2 half partials, square,
// accumulate; write mean. Deterministic fixed-order reduction.
__global__ __launch_bounds__(1024) void reduce_mean_kernel(
    const float* __restrict__ part, float* __restrict__ out, int B) {
    float s = 0.0f;
    for (int b = threadIdx.x; b < B; b += 1024) {
        float tot = part[b] + part[B + b];
        s += tot * tot;
    }
    for (int o = 32; o > 0; o >>= 1) s += __shfl_down(s, o);
    __shared__ float lds[16];
    const int lane = threadIdx.x & 63;
    const int wid = threadIdx.x >> 6;
    if (lane == 0) lds[wid] = s;
    __syncthreads();
    if (threadIdx.x == 0) {
        float total = 0.0f;
        for (int w = 0; w < 16; ++w) total += lds[w];
        out[0] = total / (float)B;
    }
}

extern "C" void kernel_launch(void* const* d_in, const int* in_sizes, int n_in,
                              void* d_out, int out_size, void* d_ws, size_t ws_size,
                              hipStream_t stream) {
    const float* yp = (const float*)d_in[0];
    const float* yt = (const float*)d_in[1];
    const int* fidx = (const int*)d_in[2];
    float* out = (float*)d_out;
    float* part = (float*)d_ws;          // 2*B floats

    const int B = in_sizes[2];           // 8192
    const int N = in_sizes[0] / B;       // 4096

    half_integral_kernel<<<B * 2, BLOCK, 0, stream>>>(yp, yt, fidx, part, N, B);
    reduce_mean_kernel<<<1, 1024, 0, stream>>>(part, out, B);
}

// Round 7
// 27.308 us; speedup vs baseline: 1.8323x; 1.1566x over previous
//
#include <hip/hip_runtime.h>
#include <hip/hip_bf16.h>

#define BLOCK 256

// trapz weight for element j of a row with fracture index id (id > 0):
//   j > id  -> 0 ;  j == 0 or j == id -> 0.5 ;  else 1
__device__ __forceinline__ float trapz_w(int j, int id) {
    return (j > id) ? 0.0f : ((j == 0 || j == id) ? 0.5f : 1.0f);
}

// Kernel 1: one block per row, 256 threads, fully unrolled 4 chunk-pairs per
// thread (covers N up to 4096). All 8 global_load_dwordx4 issue back-to-back
// (addresses clamped to the last valid chunk; weights from the UNCLAMPED
// index zero out lanes past the prefix, and fold the 0.5 end-weights in).
// err_sq[b] = (sum_j w_j * (yp[j]-yt[j]))^2
__global__ __launch_bounds__(BLOCK) void row_integral_kernel(
    const float* __restrict__ yp, const float* __restrict__ yt,
    const int* __restrict__ fidx, float* __restrict__ err_sq, int N) {
    const int b = blockIdx.x;
    const int id = fidx[b];

    float s = 0.0f;
    if (id > 0) {
        const int nchunk = (id >> 2) + 1;   // float4 chunks covering 0..id
        const float4* __restrict__ p4 = (const float4*)(yp + (size_t)b * N);
        const float4* __restrict__ t4 = (const float4*)(yt + (size_t)b * N);
        const int cmax = nchunk - 1;

        const int c0 = threadIdx.x;
        const int c1 = threadIdx.x + 256;
        const int c2 = threadIdx.x + 512;
        const int c3 = threadIdx.x + 768;
        const int a0i = min(c0, cmax);
        const int a1i = min(c1, cmax);
        const int a2i = min(c2, cmax);
        const int a3i = min(c3, cmax);

        // 8 independent loads — issue together for max MLP
        float4 pa0 = p4[a0i];
        float4 ta0 = t4[a0i];
        float4 pa1 = p4[a1i];
        float4 ta1 = t4[a1i];
        float4 pa2 = p4[a2i];
        float4 ta2 = t4[a2i];
        float4 pa3 = p4[a3i];
        float4 ta3 = t4[a3i];

        int j;
        j = c0 << 2;
        s += trapz_w(j, id) * (pa0.x - ta0.x) + trapz_w(j + 1, id) * (pa0.y - ta0.y)
           + trapz_w(j + 2, id) * (pa0.z - ta0.z) + trapz_w(j + 3, id) * (pa0.w - ta0.w);
        j = c1 << 2;
        s += trapz_w(j, id) * (pa1.x - ta1.x) + trapz_w(j + 1, id) * (pa1.y - ta1.y)
           + trapz_w(j + 2, id) * (pa1.z - ta1.z) + trapz_w(j + 3, id) * (pa1.w - ta1.w);
        j = c2 << 2;
        s += trapz_w(j, id) * (pa2.x - ta2.x) + trapz_w(j + 1, id) * (pa2.y - ta2.y)
           + trapz_w(j + 2, id) * (pa2.z - ta2.z) + trapz_w(j + 3, id) * (pa2.w - ta2.w);
        j = c3 << 2;
        s += trapz_w(j, id) * (pa3.x - ta3.x) + trapz_w(j + 1, id) * (pa3.y - ta3.y)
           + trapz_w(j + 2, id) * (pa3.z - ta3.z) + trapz_w(j + 3, id) * (pa3.w - ta3.w);
    }

    // wave64 reduce
    for (int o = 32; o > 0; o >>= 1) s += __shfl_down(s, o);

    __shared__ float part[4];
    const int lane = threadIdx.x & 63;
    const int wid = threadIdx.x >> 6;
    if (lane == 0) part[wid] = s;
    __syncthreads();
    if (threadIdx.x == 0) {
        float total = part[0] + part[1] + part[2] + part[3];
        err_sq[b] = total * total;
    }
}

// Kernel 2: single block, deterministic reduction of B floats -> mean.
__global__ __launch_bounds__(1024) void reduce_mean_kernel(
    const float* __restrict__ err_sq, float* __restrict__ out, int B) {
    const float4* __restrict__ e4 = (const float4*)err_sq;
    const int n4 = B >> 2;
    float s = 0.0f;
    for (int i = threadIdx.x; i < n4; i += 1024) {
        float4 v = e4[i];
        s += (v.x + v.y) + (v.z + v.w);
    }
    for (int i = (n4 << 2) + threadIdx.x; i < B; i += 1024) s += err_sq[i];

    for (int o = 32; o > 0; o >>= 1) s += __shfl_down(s, o);
    __shared__ float part[16];
    const int lane = threadIdx.x & 63;
    const int wid = threadIdx.x >> 6;
    if (lane == 0) part[wid] = s;
    __syncthreads();
    if (threadIdx.x == 0) {
        float total = 0.0f;
        for (int w = 0; w < 16; ++w) total += part[w];
        out[0] = total / (float)B;
    }
}

extern "C" void kernel_launch(void* const* d_in, const int* in_sizes, int n_in,
                              void* d_out, int out_size, void* d_ws, size_t ws_size,
                              hipStream_t stream) {
    const float* yp = (const float*)d_in[0];
    const float* yt = (const float*)d_in[1];
    const int* fidx = (const int*)d_in[2];
    float* out = (float*)d_out;
    float* err_sq = (float*)d_ws;

    const int B = in_sizes[2];           // 8192
    const int N = in_sizes[0] / B;       // 4096 (kernel assumes N <= 4096)

    row_integral_kernel<<<B, BLOCK, 0, stream>>>(yp, yt, fidx, err_sq, N);
    reduce_mean_kernel<<<1, 1024, 0, stream>>>(err_sq, out, B);
}

// Round 8
// 27.143 us; speedup vs baseline: 1.8435x; 1.0061x over previous
//
#include <hip/hip_runtime.h>
#include <hip/hip_bf16.h>

// trapz weight for element j of a row with fracture index id (id > 0):
//   j > id  -> 0 ;  j == 0 or j == id -> 0.5 ;  else 1
__device__ __forceinline__ float trapz_w(int j, int id) {
    return (j > id) ? 0.0f : ((j == 0 || j == id) ? 0.5f : 1.0f);
}

// Kernel 1: 2 rows per block, 512 threads (256 per row). Each row-subblock:
// fully unrolled 4 chunk-pairs per thread (covers N up to 4096), addresses
// clamped to the last valid chunk; weights from the UNCLAMPED index zero out
// lanes past the prefix and fold in the 0.5 end-weights.
// err_sq[row] = (sum_j w_j * (yp[j]-yt[j]))^2
__global__ __launch_bounds__(512) void row_integral_kernel(
    const float* __restrict__ yp, const float* __restrict__ yt,
    const int* __restrict__ fidx, float* __restrict__ err_sq, int N) {
    const int r = threadIdx.x >> 8;                 // 0..1: row within block
    const int tid = threadIdx.x & 255;              // 0..255 within row
    const int b = (blockIdx.x << 1) + r;            // global row
    const int id = fidx[b];

    float s = 0.0f;
    if (id > 0) {
        const int nchunk = (id >> 2) + 1;   // float4 chunks covering 0..id
        const float4* __restrict__ p4 = (const float4*)(yp + (size_t)b * N);
        const float4* __restrict__ t4 = (const float4*)(yt + (size_t)b * N);
        const int cmax = nchunk - 1;

        const int c0 = tid;
        const int c1 = tid + 256;
        const int c2 = tid + 512;
        const int c3 = tid + 768;
        const int a0i = min(c0, cmax);
        const int a1i = min(c1, cmax);
        const int a2i = min(c2, cmax);
        const int a3i = min(c3, cmax);

        // 8 independent loads — issue together for max MLP
        float4 pa0 = p4[a0i];
        float4 ta0 = t4[a0i];
        float4 pa1 = p4[a1i];
        float4 ta1 = t4[a1i];
        float4 pa2 = p4[a2i];
        float4 ta2 = t4[a2i];
        float4 pa3 = p4[a3i];
        float4 ta3 = t4[a3i];

        int j;
        j = c0 << 2;
        s += trapz_w(j, id) * (pa0.x - ta0.x) + trapz_w(j + 1, id) * (pa0.y - ta0.y)
           + trapz_w(j + 2, id) * (pa0.z - ta0.z) + trapz_w(j + 3, id) * (pa0.w - ta0.w);
        j = c1 << 2;
        s += trapz_w(j, id) * (pa1.x - ta1.x) + trapz_w(j + 1, id) * (pa1.y - ta1.y)
           + trapz_w(j + 2, id) * (pa1.z - ta1.z) + trapz_w(j + 3, id) * (pa1.w - ta1.w);
        j = c2 << 2;
        s += trapz_w(j, id) * (pa2.x - ta2.x) + trapz_w(j + 1, id) * (pa2.y - ta2.y)
           + trapz_w(j + 2, id) * (pa2.z - ta2.z) + trapz_w(j + 3, id) * (pa2.w - ta2.w);
        j = c3 << 2;
        s += trapz_w(j, id) * (pa3.x - ta3.x) + trapz_w(j + 1, id) * (pa3.y - ta3.y)
           + trapz_w(j + 2, id) * (pa3.z - ta3.z) + trapz_w(j + 3, id) * (pa3.w - ta3.w);
    }

    // wave64 reduce
    for (int o = 32; o > 0; o >>= 1) s += __shfl_down(s, o);

    __shared__ float part[8];                       // 4 waves per row, 2 rows
    const int lane = threadIdx.x & 63;
    const int wid = threadIdx.x >> 6;               // 0..7 block-wide
    if (lane == 0) part[wid] = s;
    __syncthreads();
    if (tid == 0) {
        const int o4 = r << 2;
        float total = (part[o4] + part[o4 + 1]) + (part[o4 + 2] + part[o4 + 3]);
        err_sq[b] = total * total;
    }
}

// Kernel 2: single block, deterministic reduction of B floats -> mean.
__global__ __launch_bounds__(1024) void reduce_mean_kernel(
    const float* __restrict__ err_sq, float* __restrict__ out, int B) {
    const float4* __restrict__ e4 = (const float4*)err_sq;
    const int n4 = B >> 2;
    float s = 0.0f;
    for (int i = threadIdx.x; i < n4; i += 1024) {
        float4 v = e4[i];
        s += (v.x + v.y) + (v.z + v.w);
    }
    for (int i = (n4 << 2) + threadIdx.x; i < B; i += 1024) s += err_sq[i];

    for (int o = 32; o > 0; o >>= 1) s += __shfl_down(s, o);
    __shared__ float part[16];
    const int lane = threadIdx.x & 63;
    const int wid = threadIdx.x >> 6;
    if (lane == 0) part[wid] = s;
    __syncthreads();
    if (threadIdx.x == 0) {
        float total = 0.0f;
        for (int w = 0; w < 16; ++w) total += part[w];
        out[0] = total / (float)B;
    }
}

extern "C" void kernel_launch(void* const* d_in, const int* in_sizes, int n_in,
                              void* d_out, int out_size, void* d_ws, size_t ws_size,
                              hipStream_t stream) {
    const float* yp = (const float*)d_in[0];
    const float* yt = (const float*)d_in[1];
    const int* fidx = (const int*)d_in[2];
    float* out = (float*)d_out;
    float* err_sq = (float*)d_ws;

    const int B = in_sizes[2];           // 8192
    const int N = in_sizes[0] / B;       // 4096 (kernel assumes N <= 4096)

    row_integral_kernel<<<B / 2, 512, 0, stream>>>(yp, yt, fidx, err_sq, N);
    reduce_mean_kernel<<<1, 1024, 0, stream>>>(err_sq, out, B);
}